// Round 2
// baseline (127.894 us; speedup 1.0000x reference)
//
#include <hip/hip_runtime.h>

// out[b,v,c] = sum_k evecs[b,v,k]^2 * exp(-evals[b,k] * scale[c])
// scale[c] = 10^(-2 + 2c/15), c in [0,16)
// B=8, V=50000, K=128, COUNT=16. All fp32.
//
// R1: register-tile TILE=4 rows/thread so each wave-uniform ds_read_b128 of
// the coef table feeds 16 FMAs (was 4). R0 was LDS-return-BW bound:
// 24.5 waves/CU * 512 b128 * 12cyc = 62.5us == measured 65us.

constexpr int B_   = 8;
constexpr int V_   = 50000;
constexpr int K_   = 128;
constexpr int CNT  = 16;
constexpr int TPB  = 128;
constexpr int TILE = 4;
constexpr int ROWS_PER_BLOCK = TPB * TILE;  // 512

__global__ __launch_bounds__(TPB) void hks_heat_kernel(
    const float* __restrict__ evals,   // [B, K]
    const float* __restrict__ evecs,   // [B, V, K]
    float* __restrict__ out)           // [B, V, CNT]
{
    __shared__ float4 coef4[CNT * K_ / 4];  // 8 KB
    float* coef = (float*)coef4;

    const int b = blockIdx.y;

    // Fill coef table: 2048 entries, 128 threads -> 16 each (once per block).
    for (int i = threadIdx.x; i < CNT * K_; i += TPB) {
        const int c = i >> 7;        // i / 128
        const int k = i & (K_ - 1);  // i % 128
        const float s = powf(10.0f, -2.0f + (float)c * (2.0f / 15.0f));
        coef[i] = expf(-evals[b * K_ + k] * s);
    }
    __syncthreads();

    const int v0 = blockIdx.x * ROWS_PER_BLOCK + threadIdx.x;

    const float4* __restrict__ row[TILE];
    bool valid[TILE];
#pragma unroll
    for (int r = 0; r < TILE; ++r) {
        const int v = v0 + r * TPB;
        valid[r] = (v < V_);
        // Clamp address so speculative loads stay in-bounds; stores are predicated.
        const int vc = valid[r] ? v : (V_ - 1);
        row[r] = (const float4*)(evecs + ((long)b * V_ + vc) * K_);
    }

    float acc[TILE][CNT];
#pragma unroll
    for (int r = 0; r < TILE; ++r)
#pragma unroll
        for (int c = 0; c < CNT; ++c) acc[r][c] = 0.0f;

#pragma unroll 2
    for (int j = 0; j < K_ / 4; ++j) {
        float sx[TILE], sy[TILE], sz[TILE], sw[TILE];
#pragma unroll
        for (int r = 0; r < TILE; ++r) {
            const float4 e = row[r][j];
            sx[r] = e.x * e.x;
            sy[r] = e.y * e.y;
            sz[r] = e.z * e.z;
            sw[r] = e.w * e.w;
        }
#pragma unroll
        for (int c = 0; c < CNT; ++c) {
            // Wave-uniform address -> LDS broadcast, conflict-free; one read
            // feeds TILE*4 = 16 FMAs.
            const float4 q = coef4[c * (K_ / 4) + j];
#pragma unroll
            for (int r = 0; r < TILE; ++r) {
                acc[r][c] += sx[r] * q.x;
                acc[r][c] += sy[r] * q.y;
                acc[r][c] += sz[r] * q.z;
                acc[r][c] += sw[r] * q.w;
            }
        }
    }

#pragma unroll
    for (int r = 0; r < TILE; ++r) {
        if (!valid[r]) continue;
        const int v = v0 + r * TPB;
        float4* o = (float4*)(out + ((long)b * V_ + v) * CNT);
#pragma unroll
        for (int q = 0; q < 4; ++q)
            o[q] = make_float4(acc[r][4 * q + 0], acc[r][4 * q + 1],
                               acc[r][4 * q + 2], acc[r][4 * q + 3]);
    }
}

extern "C" void kernel_launch(void* const* d_in, const int* in_sizes, int n_in,
                              void* d_out, int out_size, void* d_ws, size_t ws_size,
                              hipStream_t stream) {
    const float* evals = (const float*)d_in[0];  // [8,128]
    const float* evecs = (const float*)d_in[1];  // [8,50000,128]
    float* out = (float*)d_out;                  // [8,50000,16]

    dim3 grid((V_ + ROWS_PER_BLOCK - 1) / ROWS_PER_BLOCK, B_);
    hks_heat_kernel<<<grid, TPB, 0, stream>>>(evals, evecs, out);
}